// Round 7
// baseline (31.564 us; speedup 1.0000x reference)
//
#include <hip/hip_runtime.h>

namespace {
constexpr int C  = 12;
constexpr int D  = 8;
constexpr int HI = 16;
constexpr int WI = 16;
constexpr int IMG_H = 1080;
constexpr int IMG_W = 1920;
constexpr int PIX = IMG_H * IMG_W;
constexpr int DSTRIDE = WI * C + 4;       // 196 dwords: de-alias z-slabs, 16B-aligned rows
constexpr int ROWTAB  = D * DSTRIDE;      // 1568 floats per row table
constexpr int PX_PER_BLOCK = 1024;        // 256 threads x 4 px
constexpr int NBLOCKS = PIX / PX_PER_BLOCK; // 2025 exactly
constexpr int WQ = IMG_W / 4;             // 480 column-quads

typedef float f32x4 __attribute__((ext_vector_type(4)));
typedef float f32x2 __attribute__((ext_vector_type(2)));

__device__ __forceinline__ f32x2 vlo(f32x4 v) { return __builtin_shufflevector(v, v, 0, 1); }
__device__ __forceinline__ f32x2 vhi(f32x4 v) { return __builtin_shufflevector(v, v, 2, 3); }

// Per-column z-interp LUT: {wz0, wz1, zo0(dwords), zo1(dwords)}, validity-masked
// weights, clamped offsets. Phase-major layout: entry[(col&3)*WQ + (col>>2)] so
// phase-j loads are lane-contiguous dwordx4.
__global__ void zprep(int4* __restrict__ tz) {
    const int col = blockIdx.x * 256 + threadIdx.x;
    if (col >= IMG_W) return;
    const float wgv  = (float)col * (2.0f / (IMG_W - 1)) - 1.0f;
    const float iz   = ((wgv + 1.0f) * (float)D - 1.0f) * 0.5f;
    const float iz0f = floorf(iz);
    const float fz   = iz - iz0f;
    const int   iz0  = (int)iz0f, iz1 = iz0 + 1;
    const float wz0  = (iz0 >= 0 && iz0 < D) ? (1.0f - fz) : 0.0f;
    const float wz1  = (iz1 >= 0 && iz1 < D) ? fz : 0.0f;
    int4 e;
    e.x = __float_as_int(wz0);
    e.y = __float_as_int(wz1);
    e.z = min(max(iz0, 0), D - 1) * DSTRIDE;
    e.w = min(max(iz1, 0), D - 1) * DSTRIDE;
    tz[(col & 3) * WQ + (col >> 2)] = e;
}

__global__ __launch_bounds__(256) void slice(const float* __restrict__ grid5,
                                             const float* __restrict__ guide,
                                             const int4* __restrict__ tz,
                                             float* __restrict__ out) {
    __shared__ float gy[2 * ROWTAB];      // up to 2 row tables, 12.5 KB

    const int tid  = threadIdx.x;
    const int pblk = blockIdx.x * PX_PER_BLOCK;
    const int r0    = pblk / IMG_W;
    const int rlast = (pblk + PX_PER_BLOCK - 1) / IMG_W;
    const int nrows = rlast - r0 + 1;     // 1 or 2

    // --- phase 1: fold y-interpolation into LDS per row table ---
    for (int rr = 0; rr < nrows; ++rr) {
        const int   row  = r0 + rr;
        const float hgv  = (float)row * (2.0f / (IMG_H - 1)) - 1.0f;
        const float iy   = ((hgv + 1.0f) * (float)HI - 1.0f) * 0.5f;
        const float iy0f = floorf(iy);
        const float fy   = iy - iy0f;
        const int   iy0  = (int)iy0f, iy1 = iy0 + 1;
        const float wy0  = (iy0 >= 0 && iy0 < HI) ? (1.0f - fy) : 0.0f;
        const float wy1  = (iy1 >= 0 && iy1 < HI) ? fy : 0.0f;
        const int   y0c  = min(max(iy0, 0), HI - 1);
        const int   y1c  = min(max(iy1, 0), HI - 1);

        for (int i = tid; i < C * D * WI; i += 256) {
            const int x  = i & (WI - 1);
            const int cd = i >> 4;        // c*D + d
            const int d  = cd & (D - 1);
            const int c  = cd >> 3;
            const int gbase = ((c * D + d) * HI) * WI + x;
            const float v = wy0 * grid5[gbase + y0c * WI]
                          + wy1 * grid5[gbase + y1c * WI];
            gy[rr * ROWTAB + d * DSTRIDE + x * C + c] = v;
        }
    }
    __syncthreads();

    // --- phase 2: 4 contiguous px per thread ---
    const int p0  = pblk + tid * 4;
    const int row = p0 / IMG_W;           // uniform per thread (4 | 1920)
    const float* __restrict__ gyb = gy + (row - r0) * ROWTAB;
    const int tzi = (p0 >> 2) - row * WQ; // column-quad index

    const float4 g4 = *reinterpret_cast<const float4*>(guide + p0);
    const float gx[4] = {g4.x, g4.y, g4.z, g4.w};

    float acc[4][12];

    #pragma unroll
    for (int j = 0; j < 4; ++j) {
        const int4  ze  = tz[tzi + j * WQ];      // L1-hot, lane-contiguous
        const float wz0 = __int_as_float(ze.x);
        const float wz1 = __int_as_float(ze.y);
        const int   zo0 = ze.z, zo1 = ze.w;

        // x from guidemap value: ix = 8*g + 7.5
        const float xv   = gx[j];
        const float ix   = fmaf(xv, (float)WI * 0.5f, (float)WI * 0.5f - 0.5f);
        const float ix0f = floorf(ix);
        const float fx   = ix - ix0f;
        const int   ix0  = (int)ix0f;
        const int   ix0c = min(max(ix0, 0), WI - 1);
        const float wx0  = (ix0 >= 0 && ix0 < WI) ? (1.0f - fx) : 0.0f;
        const float fxv  = (ix0 + 1 >= 0 && ix0 + 1 < WI) ? fx : 0.0f;
        const int   xo0  = ix0c * C;
        const int   xo1  = min(ix0c + 1, WI - 1) * C;

        const float w00 = wz0 * wx0, w01 = wz0 * fxv;
        const float w10 = wz1 * wx0, w11 = wz1 * fxv;
        const f32x2 w00_2 = {w00, w00}, w01_2 = {w01, w01};
        const f32x2 w10_2 = {w10, w10}, w11_2 = {w11, w11};

        const f32x4* p00 = reinterpret_cast<const f32x4*>(&gyb[zo0 + xo0]);
        const f32x4* p01 = reinterpret_cast<const f32x4*>(&gyb[zo0 + xo1]);
        const f32x4* p10 = reinterpret_cast<const f32x4*>(&gyb[zo1 + xo0]);
        const f32x4* p11 = reinterpret_cast<const f32x4*>(&gyb[zo1 + xo1]);

        f32x4 u0 = p00[0], u1 = p00[1], u2 = p00[2];
        f32x2 a0 = w00_2 * vlo(u0), a1 = w00_2 * vhi(u0);
        f32x2 a2 = w00_2 * vlo(u1), a3 = w00_2 * vhi(u1);
        f32x2 a4 = w00_2 * vlo(u2), a5 = w00_2 * vhi(u2);

        u0 = p01[0]; u1 = p01[1]; u2 = p01[2];
        a0 = __builtin_elementwise_fma(w01_2, vlo(u0), a0);
        a1 = __builtin_elementwise_fma(w01_2, vhi(u0), a1);
        a2 = __builtin_elementwise_fma(w01_2, vlo(u1), a2);
        a3 = __builtin_elementwise_fma(w01_2, vhi(u1), a3);
        a4 = __builtin_elementwise_fma(w01_2, vlo(u2), a4);
        a5 = __builtin_elementwise_fma(w01_2, vhi(u2), a5);

        u0 = p10[0]; u1 = p10[1]; u2 = p10[2];
        a0 = __builtin_elementwise_fma(w10_2, vlo(u0), a0);
        a1 = __builtin_elementwise_fma(w10_2, vhi(u0), a1);
        a2 = __builtin_elementwise_fma(w10_2, vlo(u1), a2);
        a3 = __builtin_elementwise_fma(w10_2, vhi(u1), a3);
        a4 = __builtin_elementwise_fma(w10_2, vlo(u2), a4);
        a5 = __builtin_elementwise_fma(w10_2, vhi(u2), a5);

        u0 = p11[0]; u1 = p11[1]; u2 = p11[2];
        a0 = __builtin_elementwise_fma(w11_2, vlo(u0), a0);
        a1 = __builtin_elementwise_fma(w11_2, vhi(u0), a1);
        a2 = __builtin_elementwise_fma(w11_2, vlo(u1), a2);
        a3 = __builtin_elementwise_fma(w11_2, vhi(u1), a3);
        a4 = __builtin_elementwise_fma(w11_2, vlo(u2), a4);
        a5 = __builtin_elementwise_fma(w11_2, vhi(u2), a5);

        acc[j][0]  = a0.x; acc[j][1]  = a0.y;
        acc[j][2]  = a1.x; acc[j][3]  = a1.y;
        acc[j][4]  = a2.x; acc[j][5]  = a2.y;
        acc[j][6]  = a3.x; acc[j][7]  = a3.y;
        acc[j][8]  = a4.x; acc[j][9]  = a4.y;
        acc[j][10] = a5.x; acc[j][11] = a5.y;
    }

    #pragma unroll
    for (int c = 0; c < 12; ++c) {
        f32x4 o = { acc[0][c], acc[1][c], acc[2][c], acc[3][c] };
        __builtin_nontemporal_store(o, reinterpret_cast<f32x4*>(out + c * PIX + p0));
    }
}
} // namespace

extern "C" void kernel_launch(void* const* d_in, const int* in_sizes, int n_in,
                              void* d_out, int out_size, void* d_ws, size_t ws_size,
                              hipStream_t stream) {
    const float* grid5 = (const float*)d_in[0];   // [1,12,8,16,16] fp32
    const float* guide = (const float*)d_in[1];   // [1,1,1080,1920] fp32
    float* out = (float*)d_out;                   // [1,12,1080,1920] fp32
    int4*  tz  = (int4*)d_ws;                     // 30 KB z-LUT

    hipLaunchKernelGGL(zprep, dim3((IMG_W + 255) / 256), dim3(256), 0, stream, tz);
    hipLaunchKernelGGL(slice, dim3(NBLOCKS), dim3(256), 0, stream,
                       grid5, guide, tz, out);
}

// Round 8
// 26.643 us; speedup vs baseline: 1.1847x; 1.1847x over previous
//
#include <hip/hip_runtime.h>

namespace {
constexpr int C  = 12;
constexpr int D  = 8;
constexpr int HI = 16;
constexpr int WI = 16;
constexpr int IMG_H = 1080;
constexpr int IMG_W = 1920;
constexpr int PIX = IMG_H * IMG_W;
constexpr int DSTRIDE = WI * C + 4;       // 196 pair-entries per d-slab (16B-aligned)
constexpr int ROWTAB  = D * DSTRIDE;      // 1568 half2 entries = 6.1 KB per row
constexpr int PX_PER_BLOCK = 1024;        // 256 threads x 4 px
constexpr int NBLOCKS = PIX / PX_PER_BLOCK; // 2025 exactly

typedef float    f32x4 __attribute__((ext_vector_type(4)));
typedef _Float16 f16x2 __attribute__((ext_vector_type(2)));
typedef _Float16 f16x8 __attribute__((ext_vector_type(8)));

__device__ __forceinline__ float fdot2f(f16x2 a, f16x2 b, float c) {
#if __has_builtin(__builtin_amdgcn_fdot2)
    return __builtin_amdgcn_fdot2(a, b, c, false);   // v_dot2_f32_f16
#else
    return fmaf((float)a.x, (float)b.x, fmaf((float)a.y, (float)b.y, c));
#endif
}

__device__ __forceinline__ f16x2 pget(f16x8 v, int k) {
    return (k == 0) ? __builtin_shufflevector(v, v, 0, 1)
         : (k == 1) ? __builtin_shufflevector(v, v, 2, 3)
         : (k == 2) ? __builtin_shufflevector(v, v, 4, 5)
                    : __builtin_shufflevector(v, v, 6, 7);
}

__global__ __launch_bounds__(256) void slice(const float* __restrict__ grid5,
                                             const float* __restrict__ guide,
                                             float* __restrict__ out) {
    __shared__ f16x2 gy[2 * ROWTAB];      // up to 2 row tables, 12.5 KB

    const int tid  = threadIdx.x;
    const int pblk = blockIdx.x * PX_PER_BLOCK;
    const int p0   = pblk + tid * 4;

    // hoist guide load: independent of LDS, latency hides under phase 1
    const float4 g4 = *reinterpret_cast<const float4*>(guide + p0);

    const int r0    = pblk / IMG_W;
    const int rlast = (pblk + PX_PER_BLOCK - 1) / IMG_W;
    const int nrows = rlast - r0 + 1;     // 1 or 2

    // --- phase 1: fold y-interp into LDS, neighbor-pair fp16 layout ---
    // entry[d][x][c] = { v(x,c), v(min(x+1,15),c) }
    for (int rr = 0; rr < nrows; ++rr) {
        const int   row  = r0 + rr;
        const float hgv  = (float)row * (2.0f / (IMG_H - 1)) - 1.0f;
        const float iy   = ((hgv + 1.0f) * (float)HI - 1.0f) * 0.5f;
        const float iy0f = floorf(iy);
        const float fy   = iy - iy0f;
        const int   iy0  = (int)iy0f, iy1 = iy0 + 1;
        const float wy0  = (iy0 >= 0 && iy0 < HI) ? (1.0f - fy) : 0.0f;
        const float wy1  = (iy1 >= 0 && iy1 < HI) ? fy : 0.0f;
        const int   y0c  = min(max(iy0, 0), HI - 1);
        const int   y1c  = min(max(iy1, 0), HI - 1);

        for (int i = tid; i < C * D * WI; i += 256) {
            const int x  = i & (WI - 1);   // lane-fastest -> coalesced global reads
            const int cd = i >> 4;
            const int d  = cd & (D - 1);
            const int c  = cd >> 3;
            const int x1 = min(x + 1, WI - 1);
            const int gb = ((c * D + d) * HI) * WI;
            const float a0 = grid5[gb + y0c * WI + x];
            const float a1 = grid5[gb + y0c * WI + x1];
            const float b0 = grid5[gb + y1c * WI + x];
            const float b1 = grid5[gb + y1c * WI + x1];
            f16x2 e;
            e.x = (_Float16)(wy0 * a0 + wy1 * b0);
            e.y = (_Float16)(wy0 * a1 + wy1 * b1);
            gy[rr * ROWTAB + d * DSTRIDE + x * C + c] = e;
        }
    }
    __syncthreads();

    // --- phase 2: 4 contiguous px per thread, 6 ds_read_b128 + 24 dot2 per px ---
    const int row  = p0 / IMG_W;          // uniform per thread (4 | 1920)
    const int col0 = p0 - row * IMG_W;
    const f16x2* __restrict__ gyb = gy + (row - r0) * ROWTAB;

    const float gx[4] = {g4.x, g4.y, g4.z, g4.w};

    float acc[4][12];

    #pragma unroll
    for (int j = 0; j < 4; ++j) {
        // z (column) interpolation
        const int   w    = col0 + j;
        const float wgv  = (float)w * (2.0f / (IMG_W - 1)) - 1.0f;
        const float iz   = ((wgv + 1.0f) * (float)D - 1.0f) * 0.5f;
        const float iz0f = floorf(iz);
        const float fz   = iz - iz0f;
        const int   iz0  = (int)iz0f, iz1 = iz0 + 1;
        const float wz0  = (iz0 >= 0 && iz0 < D) ? (1.0f - fz) : 0.0f;
        const float wz1  = (iz1 >= 0 && iz1 < D) ? fz : 0.0f;
        const int   zo0  = min(max(iz0, 0), D - 1) * DSTRIDE;
        const int   zo1  = min(max(iz1, 0), D - 1) * DSTRIDE;

        // x from guidemap value: ix = 8*g + 7.5
        const float xv   = gx[j];
        const float ix   = fmaf(xv, (float)WI * 0.5f, (float)WI * 0.5f - 0.5f);
        const float ix0f = floorf(ix);
        const float fx   = ix - ix0f;
        const int   ix0  = (int)ix0f;
        const float wx0  = (ix0 >= 0 && ix0 < WI) ? (1.0f - fx) : 0.0f;
        const float wx1  = (ix0 + 1 >= 0 && ix0 + 1 < WI) ? fx : 0.0f;
        const int   xo   = min(max(ix0, 0), WI - 1) * C;

        f16x2 w0h, w1h;                    // {wz*wx0, wz*wx1} per z-slab
        w0h.x = (_Float16)(wz0 * wx0);  w0h.y = (_Float16)(wz0 * wx1);
        w1h.x = (_Float16)(wz1 * wx0);  w1h.y = (_Float16)(wz1 * wx1);

        const f16x8* q0 = reinterpret_cast<const f16x8*>(&gyb[zo0 + xo]);
        const f16x8* q1 = reinterpret_cast<const f16x8*>(&gyb[zo1 + xo]);
        const f16x8 u0 = q0[0], u1 = q0[1], u2 = q0[2];   // z0: ch 0-3, 4-7, 8-11
        const f16x8 v0 = q1[0], v1 = q1[1], v2 = q1[2];   // z1

        #pragma unroll
        for (int k = 0; k < 4; ++k) {
            acc[j][k]     = fdot2f(pget(u0, k), w0h, fdot2f(pget(v0, k), w1h, 0.0f));
            acc[j][4 + k] = fdot2f(pget(u1, k), w0h, fdot2f(pget(v1, k), w1h, 0.0f));
            acc[j][8 + k] = fdot2f(pget(u2, k), w0h, fdot2f(pget(v2, k), w1h, 0.0f));
        }
    }

    #pragma unroll
    for (int c = 0; c < 12; ++c) {
        f32x4 o = { acc[0][c], acc[1][c], acc[2][c], acc[3][c] };
        __builtin_nontemporal_store(o, reinterpret_cast<f32x4*>(out + c * PIX + p0));
    }
}
} // namespace

extern "C" void kernel_launch(void* const* d_in, const int* in_sizes, int n_in,
                              void* d_out, int out_size, void* d_ws, size_t ws_size,
                              hipStream_t stream) {
    const float* grid5 = (const float*)d_in[0];   // [1,12,8,16,16] fp32
    const float* guide = (const float*)d_in[1];   // [1,1,1080,1920] fp32
    float* out = (float*)d_out;                   // [1,12,1080,1920] fp32

    hipLaunchKernelGGL(slice, dim3(NBLOCKS), dim3(256), 0, stream,
                       grid5, guide, out);
}